// Round 8
// baseline (51.482 us; speedup 1.0000x reference)
//
#include <hip/hip_runtime.h>

#define N_INPUTS   1024
#define MAX_HIDDEN 2048
#define MAX_LAYERS 4
#define TOTAL_HIDDEN 8192
#define N_OUTPUTS  512
#define MAX_CONN   2048
#define MAX_OUT_CONN 4096
#define N_VALUES   9216
#define FB 256    // fused grid (1 block/CU — known to pass cooperative validation)
#define FT 1024   // fused block (16 waves)

typedef int   v4i __attribute__((ext_vector_type(4)));
typedef float v4f __attribute__((ext_vector_type(4)));

struct G { v4i ia; v4f wa; v4i ma; };

__device__ __forceinline__ void load_g(G& g,
        const int* __restrict__ ids, const float* __restrict__ wts,
        const int* __restrict__ cm, size_t c)
{
    g.ia = *reinterpret_cast<const v4i*>(ids + c);
    g.wa = *reinterpret_cast<const v4f*>(wts + c);
    g.ma = *reinterpret_cast<const v4i*>(cm + c);
}

__device__ __forceinline__ float dot_g(const G& g, const float* __restrict__ vals)
{
    float s = 0.f;
    s = fmaf(g.ma.x ? vals[g.ia.x] : 0.f, g.wa.x, s);
    s = fmaf(g.ma.y ? vals[g.ia.y] : 0.f, g.wa.y, s);
    s = fmaf(g.ma.z ? vals[g.ia.z] : 0.f, g.wa.z, s);
    s = fmaf(g.ma.w ? vals[g.ia.w] : 0.f, g.wa.w, s);
    return s;
}

#define KEEP_G(g) asm volatile("" : "+v"((g).ia), "+v"((g).wa), "+v"((g).ma))

__global__ void init_bar_kernel(unsigned* __restrict__ bar) {
    if (threadIdx.x < MAX_LAYERS) bar[threadIdx.x * 32] = 0u;
}

// ============================ FUSED PATH ============================
// 256 blocks x 1024 threads. Hidden: 8 neurons/block, 2 waves/neuron,
// 16 conns/lane = 4 contiguous 4-conn groups. Output: 2 neurons/block,
// 8 waves/neuron, 8 conns/lane = 2 groups.
__global__ void __launch_bounds__(FT, 4)
fused_net(const float* __restrict__ g_in,
          const int* __restrict__ h_ids, const float* __restrict__ h_w,
          const int* __restrict__ h_cm,  const int* __restrict__ h_am,
          const int* __restrict__ o_ids, const float* __restrict__ o_w,
          const int* __restrict__ o_cm,
          float* __restrict__ out, float* __restrict__ gvals,
          unsigned* __restrict__ bar)
{
    __shared__ float vals[N_VALUES];
    __shared__ float psum[16];

    const int tid  = threadIdx.x;
    const int wave = tid >> 6;
    const int lane = tid & 63;

    const size_t LSTRIDE = (size_t)MAX_HIDDEN * MAX_CONN;
    const size_t hbase = ((size_t)(blockIdx.x << 3) + (wave >> 1)) * MAX_CONN
                       + ((size_t)(wave & 1) << 10) + (lane << 2);
    const size_t obase = ((size_t)(blockIdx.x << 1) + (wave >> 3)) * MAX_OUT_CONN
                       + ((size_t)(wave & 7) << 9) + (lane << 2);

    G cur[4], nxt[4];

    // ---- prologue: issue layer-0 stream, then stage inputs+zeros ----
    #pragma unroll
    for (int j = 0; j < 4; ++j)
        load_g(cur[j], h_ids, h_w, h_cm, hbase + (size_t)(j << 8));
    KEEP_G(cur[0]); KEEP_G(cur[1]); KEEP_G(cur[2]); KEEP_G(cur[3]);

    {
        const v4f* in4 = reinterpret_cast<const v4f*>(g_in);
        v4f* s4 = reinterpret_cast<v4f*>(vals);
        for (int i = tid; i < (N_VALUES >> 2); i += FT) {
            v4f v;
            if (i < (N_INPUTS >> 2)) v = in4[i];
            else { v.x = 0.f; v.y = 0.f; v.z = 0.f; v.w = 0.f; }
            s4[i] = v;
        }
    }
    __syncthreads();

    #pragma unroll
    for (int k = 0; k < MAX_LAYERS; ++k) {
        // ---- compute layer k ----
        float sum = 0.f;
        #pragma unroll
        for (int j = 0; j < 4; ++j) sum += dot_g(cur[j], vals);

        #pragma unroll
        for (int off = 32; off > 0; off >>= 1)
            sum += __shfl_xor(sum, off, 64);

        if (lane == 0) psum[wave] = sum;
        __syncthreads();

        // ---- publish activations: relaxed agent exchange (at coherence point) ----
        if (tid < 8) {
            const int n = k * MAX_HIDDEN + (blockIdx.x << 3) + tid;
            float s = psum[tid << 1] + psum[(tid << 1) + 1];
            float a = tanhf(s);
            if (h_am[n] == 0) a = 0.f;
            (void)__hip_atomic_exchange(&gvals[n], a, __ATOMIC_RELAXED,
                                        __HIP_MEMORY_SCOPE_AGENT);
        }

        // ---- prefetch ALL of next stream before the barrier (pinned) ----
        if (k < MAX_LAYERS - 1) {
            #pragma unroll
            for (int j = 0; j < 4; ++j)
                load_g(nxt[j], h_ids, h_w, h_cm,
                       (size_t)(k + 1) * LSTRIDE + hbase + (size_t)(j << 8));
            KEEP_G(nxt[0]); KEEP_G(nxt[1]); KEEP_G(nxt[2]); KEEP_G(nxt[3]);
        } else {
            load_g(nxt[0], o_ids, o_w, o_cm, obase);
            load_g(nxt[1], o_ids, o_w, o_cm, obase + 256);
            KEEP_G(nxt[0]); KEEP_G(nxt[1]);
        }

        // ---- lightweight grid barrier: relaxed arrive + relaxed spin ----
        __syncthreads();
        if (tid == 0) {
            __builtin_amdgcn_s_waitcnt(0);     // publish exchanges ack'd at LLC
            asm volatile("" ::: "memory");
            __hip_atomic_fetch_add(&bar[k * 32], 1u, __ATOMIC_RELAXED,
                                   __HIP_MEMORY_SCOPE_AGENT);
            while (__hip_atomic_load(&bar[k * 32], __ATOMIC_RELAXED,
                                     __HIP_MEMORY_SCOPE_AGENT) != FB)
                __builtin_amdgcn_s_sleep(2);
            asm volatile("" ::: "memory");
        }
        __syncthreads();

        // ---- stage layer k activations (relaxed agent atomic loads: coherent) ----
        for (int i = tid; i < MAX_HIDDEN; i += FT)
            vals[N_INPUTS + k * MAX_HIDDEN + i] =
                __hip_atomic_load(&gvals[k * MAX_HIDDEN + i], __ATOMIC_RELAXED,
                                  __HIP_MEMORY_SCOPE_AGENT);
        __syncthreads();

        #pragma unroll
        for (int j = 0; j < 4; ++j) cur[j] = nxt[j];
    }

    // ---- output layer ----
    {
        float sum = dot_g(cur[0], vals) + dot_g(cur[1], vals);
        #pragma unroll
        for (int off = 32; off > 0; off >>= 1)
            sum += __shfl_xor(sum, off, 64);
        if (lane == 0) psum[wave] = sum;
        __syncthreads();
        if (tid < 2) {
            float s = 0.f;
            #pragma unroll
            for (int q = 0; q < 8; ++q) s += psum[(tid << 3) + q];
            out[(blockIdx.x << 1) + tid] = s;
        }
    }
}

// ======================= FALLBACK (round-6, 51.3us) =======================
__device__ __forceinline__ void stage_values(float* __restrict__ vals,
                                             const float* __restrict__ g_in,
                                             const float* __restrict__ gvals,
                                             int staged_hidden)
{
    const float4* in4 = reinterpret_cast<const float4*>(g_in);
    const float4* gv4 = reinterpret_cast<const float4*>(gvals);
    float4* s4 = reinterpret_cast<float4*>(vals);
    const int nin4 = N_INPUTS >> 2;
    const int pre4 = (N_INPUTS + staged_hidden) >> 2;
    for (int i = threadIdx.x; i < (N_VALUES >> 2); i += blockDim.x) {
        float4 v;
        if (i < nin4)      v = in4[i];
        else if (i < pre4) v = gv4[i - nin4];
        else { v.x = 0.f; v.y = 0.f; v.z = 0.f; v.w = 0.f; }
        s4[i] = v;
    }
}

__device__ __forceinline__ float dot4(int4 ia, float4 wa, int4 ma,
                                      const float* __restrict__ vals)
{
    float s = 0.f;
    s = fmaf(ma.x ? vals[ia.x] : 0.f, wa.x, s);
    s = fmaf(ma.y ? vals[ia.y] : 0.f, wa.y, s);
    s = fmaf(ma.z ? vals[ia.z] : 0.f, wa.z, s);
    s = fmaf(ma.w ? vals[ia.w] : 0.f, wa.w, s);
    return s;
}

__global__ void __launch_bounds__(1024, 8)
hidden_layer_kernel(const float* __restrict__ g_in,
                    float* __restrict__ gvals,
                    const int* __restrict__ ids,
                    const float* __restrict__ wts,
                    const int* __restrict__ cmask,
                    const int* __restrict__ amask,
                    int row_base)
{
    __shared__ float vals[N_VALUES];
    __shared__ float psum[16];

    const int tid  = threadIdx.x;
    const int wave = tid >> 6;
    const int lane = tid & 63;

    const int neuron = (blockIdx.x << 2) + (wave >> 2);
    const int q      = wave & 3;
    const size_t c0  = (size_t)(row_base + neuron) * MAX_CONN + (q << 9) + (lane << 2);

    int4   ia0 = *reinterpret_cast<const int4*>(ids + c0);
    float4 wa0 = *reinterpret_cast<const float4*>(wts + c0);
    int4   ma0 = *reinterpret_cast<const int4*>(cmask + c0);
    int4   ia1 = *reinterpret_cast<const int4*>(ids + c0 + 256);
    float4 wa1 = *reinterpret_cast<const float4*>(wts + c0 + 256);
    int4   ma1 = *reinterpret_cast<const int4*>(cmask + c0 + 256);

    stage_values(vals, g_in, gvals, row_base);
    __syncthreads();

    float sum = dot4(ia0, wa0, ma0, vals) + dot4(ia1, wa1, ma1, vals);

    #pragma unroll
    for (int off = 32; off > 0; off >>= 1)
        sum += __shfl_xor(sum, off, 64);

    if (lane == 0) psum[wave] = sum;
    __syncthreads();

    if (tid < 4) {
        const int n = (blockIdx.x << 2) + tid;
        float s = psum[(tid << 2)] + psum[(tid << 2) + 1]
                + psum[(tid << 2) + 2] + psum[(tid << 2) + 3];
        float a = tanhf(s);
        if (amask[row_base + n] == 0) a = 0.f;
        gvals[row_base + n] = a;
    }
}

__global__ void __launch_bounds__(1024, 8)
output_layer_kernel(const float* __restrict__ g_in,
                    const float* __restrict__ gvals,
                    const int* __restrict__ ids,
                    const float* __restrict__ wts,
                    const int* __restrict__ cmask,
                    float* __restrict__ out)
{
    __shared__ float vals[N_VALUES];
    __shared__ float psum[16];

    const int tid  = threadIdx.x;
    const int wave = tid >> 6;
    const int lane = tid & 63;

    const size_t c0 = (size_t)blockIdx.x * MAX_OUT_CONN + (wave << 8) + (lane << 2);

    int4   ia = *reinterpret_cast<const int4*>(ids + c0);
    float4 wa = *reinterpret_cast<const float4*>(wts + c0);
    int4   ma = *reinterpret_cast<const int4*>(cmask + c0);

    stage_values(vals, g_in, gvals, TOTAL_HIDDEN);
    __syncthreads();

    float sum = dot4(ia, wa, ma, vals);

    #pragma unroll
    for (int off = 32; off > 0; off >>= 1)
        sum += __shfl_xor(sum, off, 64);

    if (lane == 0) psum[wave] = sum;
    __syncthreads();

    if (tid == 0) {
        float s = 0.f;
        #pragma unroll
        for (int q = 0; q < 16; ++q) s += psum[q];
        out[blockIdx.x] = s;
    }
}

extern "C" void kernel_launch(void* const* d_in, const int* in_sizes, int n_in,
                              void* d_out, int out_size, void* d_ws, size_t ws_size,
                              hipStream_t stream) {
    const float* input_values = (const float*)d_in[0];
    const int*   h_ids        = (const int*)d_in[1];
    const float* h_w          = (const float*)d_in[2];
    const int*   h_cm         = (const int*)d_in[3];
    const int*   h_am         = (const int*)d_in[4];
    const int*   o_ids        = (const int*)d_in[5];
    const float* o_w          = (const float*)d_in[6];
    const int*   o_cm         = (const int*)d_in[7];
    float*    out   = (float*)d_out;
    float*    gvals = (float*)d_ws;                      // 8192 activations
    unsigned* bar   = (unsigned*)(gvals + TOTAL_HIDDEN); // 4 counters, 128B apart

    // Capture-safe host-side occupancy check: can the fused kernel be
    // cooperatively resident at 1 block/CU x 256 CUs?
    int nb = 0;
    (void)hipOccupancyMaxActiveBlocksPerMultiprocessor(&nb, fused_net, FT, 0);

    if (nb >= 1) {
        init_bar_kernel<<<1, 64, 0, stream>>>(bar);
        void* args[] = { (void*)&input_values, (void*)&h_ids, (void*)&h_w, (void*)&h_cm,
                         (void*)&h_am, (void*)&o_ids, (void*)&o_w, (void*)&o_cm,
                         (void*)&out, (void*)&gvals, (void*)&bar };
        hipLaunchCooperativeKernel((const void*)fused_net, dim3(FB), dim3(FT),
                                   args, 0, stream);
    } else {
        for (int k = 0; k < MAX_LAYERS; ++k)
            hidden_layer_kernel<<<512, 1024, 0, stream>>>(
                input_values, gvals, h_ids, h_w, h_cm, h_am, k * MAX_HIDDEN);
        output_layer_kernel<<<512, 1024, 0, stream>>>(
            input_values, gvals, o_ids, o_w, o_cm, out);
    }
}

// Round 9
// 48.134 us; speedup vs baseline: 1.0696x; 1.0696x over previous
//
#include <hip/hip_runtime.h>

#define N_INPUTS   1024
#define MAX_HIDDEN 2048
#define MAX_LAYERS 4
#define TOTAL_HIDDEN 8192
#define N_OUTPUTS  512
#define MAX_CONN   2048
#define MAX_OUT_CONN 4096
#define N_VALUES   9216

// Masked, bounds-checked 4-conn dot: ids >= bound refer to not-yet-computed
// layers whose value is semantically zero (no LDS zero-fill needed).
__device__ __forceinline__ float dot4b(int4 ia, float4 wa, int4 ma,
                                       const float* __restrict__ vals, int bound)
{
    float s = 0.f;
    s = fmaf((ma.x && ia.x < bound) ? vals[ia.x] : 0.f, wa.x, s);
    s = fmaf((ma.y && ia.y < bound) ? vals[ia.y] : 0.f, wa.y, s);
    s = fmaf((ma.z && ia.z < bound) ? vals[ia.z] : 0.f, wa.z, s);
    s = fmaf((ma.w && ia.w < bound) ? vals[ia.w] : 0.f, wa.w, s);
    return s;
}

__device__ __forceinline__ float dot4(int4 ia, float4 wa, int4 ma,
                                      const float* __restrict__ vals)
{
    float s = 0.f;
    s = fmaf(ma.x ? vals[ia.x] : 0.f, wa.x, s);
    s = fmaf(ma.y ? vals[ia.y] : 0.f, wa.y, s);
    s = fmaf(ma.z ? vals[ia.z] : 0.f, wa.z, s);
    s = fmaf(ma.w ? vals[ia.w] : 0.f, wa.w, s);
    return s;
}

// Hidden layer: 2048 neurons x 2048 conns. 1024 blocks x 512 threads
// (4 blocks/CU, 32 waves/CU). 2 neurons/block, 4 waves/neuron, 8 conns/lane
// as 2 contiguous 4-conn groups (each VMEM inst covers a contiguous 1KB).
// LDS staged with the [0, 1024+row_base) prefix ONLY; gathers bound-check.
__global__ void __launch_bounds__(512, 8)
hidden_layer_kernel(const float* __restrict__ g_in,
                    float* __restrict__ gvals,
                    const int* __restrict__ ids,
                    const float* __restrict__ wts,
                    const int* __restrict__ cmask,
                    const int* __restrict__ amask,
                    int row_base)
{
    __shared__ float vals[N_VALUES];
    __shared__ float psum[8];

    const int tid  = threadIdx.x;
    const int wave = tid >> 6;
    const int lane = tid & 63;

    const int neuron = (blockIdx.x << 1) + (wave >> 2);
    const int q      = wave & 3;
    const size_t c0  = (size_t)(row_base + neuron) * MAX_CONN + (q << 9) + (lane << 2);

    // ---- issue stream loads first (in flight during LDS staging) ----
    int4   ia0 = *reinterpret_cast<const int4*>(ids + c0);
    float4 wa0 = *reinterpret_cast<const float4*>(wts + c0);
    int4   ma0 = *reinterpret_cast<const int4*>(cmask + c0);
    int4   ia1 = *reinterpret_cast<const int4*>(ids + c0 + 256);
    float4 wa1 = *reinterpret_cast<const float4*>(wts + c0 + 256);
    int4   ma1 = *reinterpret_cast<const int4*>(cmask + c0 + 256);

    // ---- stage prefix only: inputs + already-computed layers ----
    const int bound = N_INPUTS + row_base;
    {
        const float4* in4 = reinterpret_cast<const float4*>(g_in);
        const float4* gv4 = reinterpret_cast<const float4*>(gvals);
        float4* s4 = reinterpret_cast<float4*>(vals);
        const int nin4 = N_INPUTS >> 2;
        const int pre4 = bound >> 2;
        for (int i = tid; i < pre4; i += 512)
            s4[i] = (i < nin4) ? in4[i] : gv4[i - nin4];
    }
    __syncthreads();

    float sum = dot4b(ia0, wa0, ma0, vals, bound)
              + dot4b(ia1, wa1, ma1, vals, bound);

    #pragma unroll
    for (int off = 32; off > 0; off >>= 1)
        sum += __shfl_xor(sum, off, 64);

    if (lane == 0) psum[wave] = sum;
    __syncthreads();

    if (tid < 2) {
        const int n = (blockIdx.x << 1) + tid;
        float s = psum[(tid << 2)] + psum[(tid << 2) + 1]
                + psum[(tid << 2) + 2] + psum[(tid << 2) + 3];
        float a = tanhf(s);
        if (amask[row_base + n] == 0) a = 0.f;
        gvals[row_base + n] = a;
    }
}

// Output layer: 512 neurons x 4096 conns. 512 blocks x 512 threads.
// 1 neuron/block, 8 waves, 8 conns/lane as 2 contiguous groups. Full staging.
__global__ void __launch_bounds__(512, 8)
output_layer_kernel(const float* __restrict__ g_in,
                    const float* __restrict__ gvals,
                    const int* __restrict__ ids,
                    const float* __restrict__ wts,
                    const int* __restrict__ cmask,
                    float* __restrict__ out)
{
    __shared__ float vals[N_VALUES];
    __shared__ float psum[8];

    const int tid  = threadIdx.x;
    const int wave = tid >> 6;
    const int lane = tid & 63;

    const size_t c0 = (size_t)blockIdx.x * MAX_OUT_CONN + (wave << 9) + (lane << 2);

    int4   ia0 = *reinterpret_cast<const int4*>(ids + c0);
    float4 wa0 = *reinterpret_cast<const float4*>(wts + c0);
    int4   ma0 = *reinterpret_cast<const int4*>(cmask + c0);
    int4   ia1 = *reinterpret_cast<const int4*>(ids + c0 + 256);
    float4 wa1 = *reinterpret_cast<const float4*>(wts + c0 + 256);
    int4   ma1 = *reinterpret_cast<const int4*>(cmask + c0 + 256);

    {
        const float4* in4 = reinterpret_cast<const float4*>(g_in);
        const float4* gv4 = reinterpret_cast<const float4*>(gvals);
        float4* s4 = reinterpret_cast<float4*>(vals);
        const int nin4 = N_INPUTS >> 2;
        for (int i = tid; i < (N_VALUES >> 2); i += 512)
            s4[i] = (i < nin4) ? in4[i] : gv4[i - nin4];
    }
    __syncthreads();

    float sum = dot4(ia0, wa0, ma0, vals) + dot4(ia1, wa1, ma1, vals);

    #pragma unroll
    for (int off = 32; off > 0; off >>= 1)
        sum += __shfl_xor(sum, off, 64);

    if (lane == 0) psum[wave] = sum;
    __syncthreads();

    if (tid == 0) {
        float s = 0.f;
        #pragma unroll
        for (int q = 0; q < 8; ++q) s += psum[q];
        out[blockIdx.x] = s;
    }
}

extern "C" void kernel_launch(void* const* d_in, const int* in_sizes, int n_in,
                              void* d_out, int out_size, void* d_ws, size_t ws_size,
                              hipStream_t stream) {
    const float* input_values = (const float*)d_in[0];
    const int*   h_ids        = (const int*)d_in[1];
    const float* h_w          = (const float*)d_in[2];
    const int*   h_cm         = (const int*)d_in[3];
    const int*   h_am         = (const int*)d_in[4];
    const int*   o_ids        = (const int*)d_in[5];
    const float* o_w          = (const float*)d_in[6];
    const int*   o_cm         = (const int*)d_in[7];
    float* out   = (float*)d_out;
    float* gvals = (float*)d_ws;   // hidden activations: 8192 floats

    for (int k = 0; k < MAX_LAYERS; ++k) {
        hidden_layer_kernel<<<1024, 512, 0, stream>>>(
            input_values, gvals, h_ids, h_w, h_cm, h_am, k * MAX_HIDDEN);
    }

    output_layer_kernel<<<512, 512, 0, stream>>>(
        input_values, gvals, o_ids, o_w, o_cm, out);
}